// Round 8
// baseline (130.967 us; speedup 1.0000x reference)
//
#include <hip/hip_runtime.h>
#include <math.h>

namespace {

constexpr int B = 2048;
constexpr int C = 20000;
constexpr int D = 512;
constexpr int LMAX = 8;

constexpr int BMt = 128, BNt = 128, BKt = 64;
constexpr int NROWT = B / BMt;               // 16 row tiles
constexpr int NPAN  = (C + BNt - 1) / BNt;   // 157 col panels (last has 32 valid)
constexpr int KST   = D / BKt;               // 8 K-steps
constexpr int CHUNKS = 1024;                 // f16x8 (16B) slots per (tile,kstep)
constexpr int NWG   = NROWT * NPAN;          // 2512 (divisible by 8 XCDs)

constexpr float S_SCALE = 30.0f;
constexpr float COS_M = 0.87758256189037271f;   // cos(0.5)
constexpr float SIN_M = 0.47942553860420301f;   // sin(0.5)
constexpr float TH    = -0.87758256189037271f;  // cos(pi - 0.5)
constexpr float MM    = 0.23971276930210156f;   // sin(pi - 0.5) * 0.5
constexpr float MFIX  = 30.0f;                  // fixed softmax shift: |logits| <= 30

typedef float f32x16 __attribute__((ext_vector_type(16)));
typedef _Float16 f16x8 __attribute__((ext_vector_type(8)));

__device__ __forceinline__ void mfma_16(f32x16& acc, f16x8 a, f16x8 b) {
    acc = __builtin_amdgcn_mfma_f32_32x32x16_f16(a, b, acc, 0, 0, 0);
}

__device__ __forceinline__ float wave_sum(float v) {
    #pragma unroll
    for (int off = 1; off < 64; off <<= 1) v += __shfl_xor(v, off, 64);
    return v;
}

// Fused norm + pack for f, pre-normalized so GEMM emits cosine directly.
// grid (NROWT, KST): block = (row tile, one k-step). Phase 1 computes all 128
// row norms (redundantly per k-step; f is tiny/L2-hot), phase 2 packs.
// Layout: Ap[rowtile][kstep][chunk q = m_frag*4 + k16][lane] (f16x8).
// Slot (q,l): row = (q>>2)*32 + (l&31), k = (q&3)*16 + (l>>5)*8 .. +8.
__global__ void pack_a_kernel(const float* __restrict__ f, f16x8* __restrict__ Ap,
                              float* __restrict__ fn) {
    __shared__ float sInv[BMt];
    const int bx = blockIdx.x, s = blockIdx.y;
    const int t = threadIdx.x, lane = t & 63, w = t >> 6;

    for (int rr = 0; rr < 32; ++rr) {                 // wave w owns rows w*32..+31
        const int lrow = w * 32 + rr;
        const int row = bx * BMt + lrow;
        const float4* p = reinterpret_cast<const float4*>(f + (size_t)row * D + lane * 8);
        const float4 a = p[0], b = p[1];
        float s2 = a.x*a.x + a.y*a.y + a.z*a.z + a.w*a.w
                 + b.x*b.x + b.y*b.y + b.z*b.z + b.w*b.w;
        s2 = wave_sum(s2);
        if (lane == 0) {
            const float nrm = sqrtf(s2);
            sInv[lrow] = 1.0f / fmaxf(nrm, 1e-8f);
            if (s == 0) fn[row] = nrm;
        }
    }
    __syncthreads();

    f16x8* blk = Ap + (size_t)(bx * KST + s) * CHUNKS;
    #pragma unroll
    for (int i = 0; i < 4; ++i) {
        const int v = i * 256 + t;
        const int q = v >> 6, l = v & 63;
        const int lrow = (q >> 2) * 32 + (l & 31);
        const int row = bx * BMt + lrow;
        const int k = s * BKt + (q & 3) * 16 + (l >> 5) * 8;
        const float4 x0 = *reinterpret_cast<const float4*>(&f[(size_t)row * D + k]);
        const float4 x1 = *reinterpret_cast<const float4*>(&f[(size_t)row * D + k + 4]);
        const float xs[8] = {x0.x, x0.y, x0.z, x0.w, x1.x, x1.y, x1.z, x1.w};
        const float sc = sInv[lrow];
        f16x8 hv;
        #pragma unroll
        for (int j = 0; j < 8; ++j) hv[j] = (_Float16)(xs[j] * sc);
        blk[v] = hv;
    }
}

// Fused norm + pack for W columns; zero-fill cols >= C.
// grid (NPAN, KST/2): each block packs 2 k-steps.
__global__ void pack_b_kernel(const float* __restrict__ wsrc, f16x8* __restrict__ Bp,
                              float* __restrict__ wn) {
    __shared__ float sInv[BNt];
    const int pan = blockIdx.x, sg = blockIdx.y;
    const int t = threadIdx.x, lane = t & 63, w = t >> 6;

    for (int rr = 0; rr < 32; ++rr) {
        const int lcol = w * 32 + rr;
        const int col = pan * BNt + lcol;
        float s2 = 0.0f;
        if (col < C) {
            const float4* p = reinterpret_cast<const float4*>(wsrc + (size_t)col * D + lane * 8);
            const float4 a = p[0], b = p[1];
            s2 = a.x*a.x + a.y*a.y + a.z*a.z + a.w*a.w
               + b.x*b.x + b.y*b.y + b.z*b.z + b.w*b.w;
        }
        s2 = wave_sum(s2);
        if (lane == 0) {
            const float nrm = sqrtf(s2);
            sInv[lcol] = (col < C) ? (1.0f / fmaxf(nrm, 1e-8f)) : 0.0f;
            if (sg == 0 && col < C) wn[col] = nrm;
        }
    }
    __syncthreads();

    for (int ss = 0; ss < 2; ++ss) {
        const int s = sg * 2 + ss;
        f16x8* blk = Bp + (size_t)(pan * KST + s) * CHUNKS;
        #pragma unroll
        for (int i = 0; i < 4; ++i) {
            const int v = i * 256 + t;
            const int q = v >> 6, l = v & 63;
            const int lcol = (q >> 2) * 32 + (l & 31);
            const int col = pan * BNt + lcol;
            const int k = s * BKt + (q & 3) * 16 + (l >> 5) * 8;
            f16x8 hv = (f16x8)0;
            if (col < C) {
                const float4 x0 = *reinterpret_cast<const float4*>(&wsrc[(size_t)col * D + k]);
                const float4 x1 = *reinterpret_cast<const float4*>(&wsrc[(size_t)col * D + k + 4]);
                const float xs[8] = {x0.x, x0.y, x0.z, x0.w, x1.x, x1.y, x1.z, x1.w};
                const float sc = sInv[lcol];
                #pragma unroll
                for (int j = 0; j < 8; ++j) hv[j] = (_Float16)(xs[j] * sc);
            }
            blk[v] = hv;
        }
    }
}

// MFMA GEMM on normalized f16 panels, fragments global->VGPR (no LDS staging).
// TRANSPOSED accumulate: mfma(b, a) puts output ROWS on lane&31, so the
// Z-partial reduction is per-lane in-register + one shfl_xor(32).
// pZ[row][panel] = sum_cols exp(30*cos - 30).
// 1-D grid 2512 with XCD-aware swizzle; 4 waves = 2x2 of 64x64 per wave.
__global__ __launch_bounds__(256) void
gemm_mfma_kernel(const f16x8* __restrict__ Ap, const f16x8* __restrict__ Bp,
                 float* __restrict__ pZ)
{
    __shared__ float sRed[BMt][2];
    const int wgid = blockIdx.x;
    const int swz = (wgid & 7) * (NWG / 8) + (wgid >> 3);   // bijective (NWG%8==0)
    const int bx = swz & 15;          // row tile
    const int by = swz >> 4;          // panel
    const int tid  = threadIdx.x;
    const int lane = tid & 63;
    const int half = lane >> 5, l31 = lane & 31;
    const int w    = tid >> 6;
    const int wm   = w >> 1;          // 0..1
    const int wnn  = w & 1;           // 0..1

    const f16x8* Aw = Ap + (size_t)bx * KST * CHUNKS + wm * 512 + lane;
    const f16x8* Bw = Bp + (size_t)by * KST * CHUNKS + wnn * 512 + lane;

    f32x16 accT00, accT01, accT10, accT11;   // [n_frag][m_frag], rows on lanes
    #pragma unroll
    for (int i = 0; i < 16; ++i) { accT00[i] = 0.f; accT01[i] = 0.f; accT10[i] = 0.f; accT11[i] = 0.f; }

    #pragma unroll 2
    for (int s = 0; s < KST; ++s) {
        const f16x8* As = Aw + s * CHUNKS;
        const f16x8* Bs = Bw + s * CHUNKS;
        #pragma unroll
        for (int k16 = 0; k16 < 4; ++k16) {
            const f16x8 a0 = As[k16 * 64];
            const f16x8 a1 = As[256 + k16 * 64];
            const f16x8 b0 = Bs[k16 * 64];
            const f16x8 b1 = Bs[256 + k16 * 64];
            mfma_16(accT00, b0, a0);  // rows wm*64+l31,    cols wnn*64 + r-map
            mfma_16(accT01, b0, a1);  // rows wm*64+32+l31, cols wnn*64 + r-map
            mfma_16(accT10, b1, a0);  // rows wm*64+l31,    cols +32
            mfma_16(accT11, b1, a1);  // rows wm*64+32+l31, cols +32
        }
    }

    // ---- epilogue: per-lane row partials, single cross-lane step ----
    float zA = 0.0f;   // row = wm*64 + l31
    float zB = 0.0f;   // row = wm*64 + 32 + l31
    const int cbase = by * BNt + wnn * 64 + 4 * half;
    #pragma unroll
    for (int r = 0; r < 16; ++r) {
        const int cb = cbase + (r & 3) + 8 * (r >> 2);
        const float eA0 = (cb      < C) ? __expf(fmaf(accT00[r], S_SCALE, -MFIX)) : 0.0f;
        const float eB0 = (cb      < C) ? __expf(fmaf(accT01[r], S_SCALE, -MFIX)) : 0.0f;
        const float eA1 = (cb + 32 < C) ? __expf(fmaf(accT10[r], S_SCALE, -MFIX)) : 0.0f;
        const float eB1 = (cb + 32 < C) ? __expf(fmaf(accT11[r], S_SCALE, -MFIX)) : 0.0f;
        zA += eA0 + eA1;
        zB += eB0 + eB1;
    }
    zA += __shfl_xor(zA, 32, 64);    // combine the two col-halves of each row
    zB += __shfl_xor(zB, 32, 64);
    if (half == 0) {
        sRed[wm * 64 + l31][wnn]      = zA;
        sRed[wm * 64 + 32 + l31][wnn] = zB;
    }
    __syncthreads();
    if (tid < BMt) {
        pZ[(size_t)(bx * BMt + tid) * NPAN + by] = sRed[tid][0] + sRed[tid][1];
    }
}

// One wave per row: sum NPAN partials (fixed shift M=30), exact fp32 target
// logits + ArcFace margin, correct Z, emit per-row loss.
__global__ void finalize_kernel(const float* __restrict__ f, const float* __restrict__ w,
                                const float* __restrict__ fn, const float* __restrict__ wn,
                                const int* __restrict__ pinds, const int* __restrict__ lengths,
                                const float* __restrict__ pZ, float* __restrict__ loss)
{
    const int b = blockIdx.x;
    const int lane = threadIdx.x;

    float Zp = 0.0f;
    for (int p = lane; p < NPAN; p += 64) Zp += pZ[(size_t)b * NPAN + p];
    Zp = wave_sum(Zp);

    const float4* fp = reinterpret_cast<const float4*>(f + (size_t)b * D);
    const float4 a0 = fp[lane * 2 + 0];
    const float4 a1 = fp[lane * 2 + 1];
    const float fnb = fn[b];
    const int len = lengths[b];

    float opl[LMAX], ops[LMAX];
    int cs[LMAX];
    #pragma unroll
    for (int j = 0; j < LMAX; ++j) {
        const int c = pinds[(size_t)b * LMAX + j];
        cs[j] = c;
        const float4* wp = reinterpret_cast<const float4*>(w + (size_t)c * D);
        const float4 w0 = wp[lane * 2 + 0];
        const float4 w1 = wp[lane * 2 + 1];
        float d = a0.x*w0.x + a0.y*w0.y + a0.z*w0.z + a0.w*w0.w
                + a1.x*w1.x + a1.y*w1.y + a1.z*w1.z + a1.w*w1.w;
        d = wave_sum(d);
        const float cosv = d / fmaxf(fnb * wn[c], 1e-8f);
        const float sine = sqrtf(fminf(fmaxf(1.0f - cosv * cosv, 0.0f), 1.0f));
        float phi = cosv * COS_M - sine * SIN_M;
        phi = (cosv > TH) ? phi : (cosv - MM);
        opl[j] = S_SCALE * cosv;
        ops[j] = S_SCALE * phi;
    }

    // correct Z for unique positive classes (margin applied), then ragged CE
    float Zc = Zp;
    for (int j = 0; j < len; ++j) {
        bool dup = false;
        for (int jj = 0; jj < j; ++jj) dup = dup || (cs[jj] == cs[j]);
        if (!dup) Zc += expf(ops[j] - MFIX) - expf(opl[j] - MFIX);
    }
    const float lZ = logf(Zc);
    float acc = 0.0f;
    for (int j = 0; j < len; ++j) acc += (MFIX + lZ - ops[j]);
    const float Lf = (float)len;
    if (lane == 0) loss[b] = acc / (Lf * Lf);
}

__global__ void reduce_kernel(const float* __restrict__ loss, float* __restrict__ out) {
    __shared__ float sdata[256];
    const int t = threadIdx.x;
    float s = 0.0f;
    for (int i = t; i < B; i += 256) s += loss[i];
    sdata[t] = s;
    __syncthreads();
    for (int off = 128; off > 0; off >>= 1) {
        if (t < off) sdata[t] += sdata[t + off];
        __syncthreads();
    }
    if (t == 0) out[0] = sdata[0] * (1.0f / (float)B);
}

} // anonymous namespace

extern "C" void kernel_launch(void* const* d_in, const int* in_sizes, int n_in,
                              void* d_out, int out_size, void* d_ws, size_t ws_size,
                              hipStream_t stream) {
    const float* f   = (const float*)d_in[0];
    // d_in[1] = labels [B,C] — not needed (reconstructed from pinds/lengths)
    const float* w   = (const float*)d_in[2];
    const int* pinds = (const int*)d_in[3];
    const int* lens  = (const int*)d_in[4];
    float* out = (float*)d_out;

    char* ws = (char*)d_ws;
    size_t off = 0;
    auto alloc = [&](size_t bytes) { void* p = ws + off; off = (off + bytes + 255) & ~(size_t)255; return p; };

    float* wn   = (float*)alloc(C * 4);
    float* fn   = (float*)alloc(B * 4);
    float* pZ   = (float*)alloc((size_t)B * NPAN * 4);
    float* loss = (float*)alloc(B * 4);
    f16x8* Ap   = (f16x8*)alloc((size_t)NROWT * KST * CHUNKS * 16);
    f16x8* Bp   = (f16x8*)alloc((size_t)NPAN  * KST * CHUNKS * 16);

    pack_a_kernel<<<dim3(NROWT, KST), 256, 0, stream>>>(f, Ap, fn);
    pack_b_kernel<<<dim3(NPAN, KST / 2), 256, 0, stream>>>(w, Bp, wn);
    gemm_mfma_kernel<<<dim3(NWG), 256, 0, stream>>>(Ap, Bp, pZ);
    finalize_kernel<<<dim3(B), 64, 0, stream>>>(f, w, fn, wn, pinds, lens, pZ, loss);
    reduce_kernel<<<dim3(1), 256, 0, stream>>>(loss, out);
}